// Round 1
// baseline (1360.277 us; speedup 1.0000x reference)
//
#include <hip/hip_runtime.h>
#include <hip/hip_bf16.h>
#include <stdint.h>

// MultiHeadSelfAttention (Swin window attn): B=2048 windows, C=512, N=49, h=8, d=64.
// Plan: f16 MFMA (16x16x32) for QKV-proj, QK^T, PV, out-proj. fp32 accum everywhere.
// ws layout: Wqkv f16 (1.5MB) | Wproj f16 (0.5MB) | bias[8][64][64] f32 (128KB, pad
// masked with -1e9) | attout f16 [B][512][49] (103MB). Total ~105MB.

#define BATCH 2048
#define CIN 512
#define NTOK 49
#define NHEAD 8

typedef __attribute__((ext_vector_type(4))) float  ffrag;
typedef __attribute__((ext_vector_type(8))) _Float16 hfrag;
typedef __attribute__((ext_vector_type(4))) float  f32x4;
typedef __attribute__((ext_vector_type(4))) unsigned short u16x4;

#define WQKV_BYTES  (1536*512*2)
#define WPROJ_OFF   ((size_t)WQKV_BYTES)
#define WPROJ_BYTES (512*512*2)
#define BIAS_OFF    (WPROJ_OFF + WPROJ_BYTES)            // 2097152
#define BIAS_BYTES  (8*64*64*4)
#define ATT_OFF     (BIAS_OFF + BIAS_BYTES)              // 2228224 (16B aligned)

// ---------------------------------------------------------------- prep ------
__global__ void prep_kernel(const float* __restrict__ qkv_w,
                            const float* __restrict__ proj_w,
                            const float* __restrict__ bias_table,
                            const int*   __restrict__ rel_index,
                            _Float16* __restrict__ wqkv,
                            _Float16* __restrict__ wproj,
                            float*    __restrict__ biasf) {
    int idx = blockIdx.x * blockDim.x + threadIdx.x;
    const int NQ = 1536*512;
    const int NP = 512*512;
    if (idx < NQ) {
        wqkv[idx] = (_Float16)qkv_w[idx];
    } else if (idx < NQ + NP) {
        int i = idx - NQ;
        wproj[i] = (_Float16)proj_w[i];
    } else if (idx < NQ + NP + 8*64*64) {
        int i = idx - NQ - NP;
        int h = i >> 12;
        int n = (i >> 6) & 63;
        int m = i & 63;
        float v;
        if (m >= NTOK)      v = -1e9f;   // masked key columns (pad)
        else if (n >= NTOK) v = 0.0f;    // pad query rows: finite, discarded later
        else                v = bias_table[rel_index[n*NTOK + m]*NHEAD + h];
        biasf[i] = v;
    }
}

// ----------------------------------------------------- fused qkv+attention --
// Grid: 2048 blocks x 256 threads (4 waves). LDS 96KB:
//   xsT  [64][512] f16  (x^T, rows=token, swizzled)   65536B
//   q_s  [64][64]  f16  (rows=token, cols=d)           8192B
//   k_s  [64][64]  f16                                 8192B
//   vT_s [64][64]  f16  (rows=d, cols=token)           8192B
//   p_s  [64][64]  f16  (rows=q-token, cols=k-token)   8192B
// Swizzle: byte_in_row ^= (row&7)<<4  (G4 pattern, conflict-free b128 reads).
__global__ __launch_bounds__(256, 1) void attn_fused_kernel(
        const float* __restrict__ x,
        const _Float16* __restrict__ wqkv,
        const float* __restrict__ biasf,
        _Float16* __restrict__ attout) {
    extern __shared__ char lds[];
    char* xsT  = lds;
    char* q_s  = lds + 65536;
    char* k_s  = lds + 65536 +  8192;
    char* vT_s = lds + 65536 + 16384;
    char* p_s  = lds + 65536 + 24576;

    const int b    = blockIdx.x;
    const int tid  = threadIdx.x;
    const int wid  = tid >> 6;
    const int lane = tid & 63;
    const int l15  = lane & 15;
    const int g    = lane >> 4;

    // ---- stage x[b] (fp32 [512][49]) -> xsT (f16, transposed, swizzled) ----
    {
        const f32x4* xb = (const f32x4*)(x + (size_t)b * (CIN*NTOK));
        #pragma unroll
        for (int it = 0; it < 25; ++it) {
            int f4 = tid + it*256;
            if (f4 < 6272) {              // 25088 floats / 4
                f32x4 v = xb[f4];
                int base = f4 * 4;
                #pragma unroll
                for (int e = 0; e < 4; ++e) {
                    int idx = base + e;
                    int c = idx / NTOK;
                    int n = idx - c*NTOK;
                    *(_Float16*)(xsT + n*1024 + ((c*2) ^ ((n&7)<<4))) = (_Float16)v[e];
                }
            }
        }
        for (int i = tid; i < 15*512; i += 256) {   // zero pad token rows 49..63
            int r = NTOK + (i >> 9);
            int c = i & 511;
            *(_Float16*)(xsT + r*1024 + ((c*2) ^ ((r&7)<<4))) = (_Float16)0.0f;
        }
    }

    const float scale = 0.125f;   // 64^-0.5

    for (int h = 0; h < NHEAD; ++h) {
        __syncthreads();   // xsT ready / previous head's readers done

        // ===== QKV GEMM: wave owns o-tiles {3*wid .. 3*wid+2} (16 outputs each)
        ffrag acc[3][4];
        #pragma unroll
        for (int j = 0; j < 3; ++j)
            #pragma unroll
            for (int t = 0; t < 4; ++t) {
                ffrag z = {0.f, 0.f, 0.f, 0.f};
                acc[j][t] = z;
            }

        const _Float16* wrow[3];
        #pragma unroll
        for (int j = 0; j < 3; ++j) {
            int ot = wid*3 + j;
            int s  = ot >> 2, lt = ot & 3;          // s: 0=q 1=k 2=v
            wrow[j] = wqkv + (size_t)(s*512 + h*64 + lt*16 + l15) * 512;
        }

        hfrag Bf[2][3];
        #pragma unroll
        for (int j = 0; j < 3; ++j)
            Bf[0][j] = *(const hfrag*)(wrow[j] + g*8);

        #pragma unroll
        for (int ks = 0; ks < 16; ++ks) {
            if (ks < 15) {
                #pragma unroll
                for (int j = 0; j < 3; ++j)
                    Bf[(ks+1)&1][j] = *(const hfrag*)(wrow[j] + (ks+1)*32 + g*8);
            }
            hfrag Af[4];
            #pragma unroll
            for (int t = 0; t < 4; ++t) {
                int row = l15 + 16*t;
                Af[t] = *(const hfrag*)(xsT + row*1024 + ((ks*64 + g*16) ^ ((l15&7)<<4)));
            }
            #pragma unroll
            for (int j = 0; j < 3; ++j)
                #pragma unroll
                for (int t = 0; t < 4; ++t)
                    acc[j][t] = __builtin_amdgcn_mfma_f32_16x16x32_f16(
                        Af[t], Bf[ks&1][j], acc[j][t], 0, 0, 0);
        }

        // epilogue: D rows = token (4g+i+16t), D cols = output-channel (l15)
        #pragma unroll
        for (int j = 0; j < 3; ++j) {
            int ot = wid*3 + j;
            int s  = ot >> 2, lt = ot & 3;
            int dd = lt*16 + l15;
            #pragma unroll
            for (int t = 0; t < 4; ++t)
                #pragma unroll
                for (int i = 0; i < 4; ++i) {
                    int n = t*16 + 4*g + i;
                    _Float16 v = (_Float16)acc[j][t][i];
                    if (s == 0)      *(_Float16*)(q_s  + n*128  + ((dd*2) ^ ((n&7)<<4)))  = v;
                    else if (s == 1) *(_Float16*)(k_s  + n*128  + ((dd*2) ^ ((n&7)<<4)))  = v;
                    else             *(_Float16*)(vT_s + dd*128 + ((n*2)  ^ ((dd&7)<<4))) = v;
                }
        }
        __syncthreads();

        // ===== S = QK^T for token-tile wid (rows 16*wid..16*wid+15)
        ffrag sacc[4];
        #pragma unroll
        for (int mt = 0; mt < 4; ++mt) { ffrag z = {0.f,0.f,0.f,0.f}; sacc[mt] = z; }

        hfrag qa[2];
        #pragma unroll
        for (int ksp = 0; ksp < 2; ++ksp) {
            int row = 16*wid + l15;
            qa[ksp] = *(const hfrag*)(q_s + row*128 + ((ksp*64 + g*16) ^ ((l15&7)<<4)));
        }
        #pragma unroll
        for (int mt = 0; mt < 4; ++mt)
            #pragma unroll
            for (int ksp = 0; ksp < 2; ++ksp) {
                int row = 16*mt + l15;
                hfrag kb = *(const hfrag*)(k_s + row*128 + ((ksp*64 + g*16) ^ ((l15&7)<<4)));
                sacc[mt] = __builtin_amdgcn_mfma_f32_16x16x32_f16(qa[ksp], kb, sacc[mt], 0, 0, 0);
            }

        // scale + bias (mask baked in), then wave-parallel softmax over cols
        float sv[4][4];
        #pragma unroll
        for (int mt = 0; mt < 4; ++mt)
            #pragma unroll
            for (int i = 0; i < 4; ++i) {
                int n = 16*wid + 4*g + i;
                int m = 16*mt + l15;
                sv[mt][i] = sacc[mt][i]*scale + biasf[h*4096 + n*64 + m];
            }

        float rmax[4], rsum[4];
        #pragma unroll
        for (int i = 0; i < 4; ++i)
            rmax[i] = fmaxf(fmaxf(sv[0][i], sv[1][i]), fmaxf(sv[2][i], sv[3][i]));
        #pragma unroll
        for (int off = 1; off <= 8; off <<= 1)
            #pragma unroll
            for (int i = 0; i < 4; ++i)
                rmax[i] = fmaxf(rmax[i], __shfl_xor(rmax[i], off));
        #pragma unroll
        for (int i = 0; i < 4; ++i) rsum[i] = 0.0f;
        #pragma unroll
        for (int mt = 0; mt < 4; ++mt)
            #pragma unroll
            for (int i = 0; i < 4; ++i) {
                float p = __expf(sv[mt][i] - rmax[i]);
                sv[mt][i] = p;
                rsum[i] += p;
            }
        #pragma unroll
        for (int off = 1; off <= 8; off <<= 1)
            #pragma unroll
            for (int i = 0; i < 4; ++i)
                rsum[i] += __shfl_xor(rsum[i], off);

        // write unnormalized P (f16); normalization folded into PV epilogue
        #pragma unroll
        for (int mt = 0; mt < 4; ++mt)
            #pragma unroll
            for (int i = 0; i < 4; ++i) {
                int n = 16*wid + 4*g + i;
                int m = 16*mt + l15;
                *(_Float16*)(p_s + n*128 + ((m*2) ^ ((n&7)<<4))) = (_Float16)sv[mt][i];
            }

        float inv[4];
        #pragma unroll
        for (int i = 0; i < 4; ++i) inv[i] = 1.0f / rsum[i];

        // ===== O = P V  (own rows only -> no barrier needed; vT_s barriered above)
        ffrag oacc[4];
        #pragma unroll
        for (int dt = 0; dt < 4; ++dt) { ffrag z = {0.f,0.f,0.f,0.f}; oacc[dt] = z; }
        hfrag pa[2];
        #pragma unroll
        for (int ksp = 0; ksp < 2; ++ksp) {
            int row = 16*wid + l15;
            pa[ksp] = *(const hfrag*)(p_s + row*128 + ((ksp*64 + g*16) ^ ((l15&7)<<4)));
        }
        #pragma unroll
        for (int dt = 0; dt < 4; ++dt)
            #pragma unroll
            for (int ksp = 0; ksp < 2; ++ksp) {
                int row = 16*dt + l15;
                hfrag vb = *(const hfrag*)(vT_s + row*128 + ((ksp*64 + g*16) ^ ((l15&7)<<4)));
                oacc[dt] = __builtin_amdgcn_mfma_f32_16x16x32_f16(pa[ksp], vb, oacc[dt], 0, 0, 0);
            }

        // attout[b][h*64+dd][n] = O[n][dd]/rowsum   (torch transpose(2,3) layout)
        #pragma unroll
        for (int dt = 0; dt < 4; ++dt) {
            int c = h*64 + dt*16 + l15;
            _Float16* outp = attout + ((size_t)b*512 + c)*NTOK;
            #pragma unroll
            for (int i = 0; i < 4; ++i) {
                int n = 16*wid + 4*g + i;
                if (n < NTOK)
                    outp[n] = (_Float16)(oacc[dt][i] * inv[i]);
            }
        }
    }
}

// ------------------------------------------------------------- out-proj -----
// Grid: 2048 blocks x 256 threads. LDS 64KB: asT [64][512] f16 swizzled.
__global__ __launch_bounds__(256, 2) void proj_kernel(
        const _Float16* __restrict__ attout,
        const _Float16* __restrict__ wproj,
        const float* __restrict__ proj_b,
        float* __restrict__ out) {
    extern __shared__ char lds[];
    char* asT = lds;

    const int b    = blockIdx.x;
    const int tid  = threadIdx.x;
    const int wid  = tid >> 6;
    const int lane = tid & 63;
    const int l15  = lane & 15;
    const int g    = lane >> 4;

    {   // stage attout[b] -> asT (transpose to [token][c], swizzled)
        const u16x4* ab4 = (const u16x4*)(attout + (size_t)b * (512*NTOK));
        #pragma unroll
        for (int it = 0; it < 25; ++it) {
            int q4 = tid + it*256;
            if (q4 < 6272) {
                u16x4 v = ab4[q4];
                int base = q4*4;
                #pragma unroll
                for (int e = 0; e < 4; ++e) {
                    int idx = base + e;
                    int c = idx / NTOK;
                    int n = idx - c*NTOK;
                    *(unsigned short*)(asT + n*1024 + ((c*2) ^ ((n&7)<<4))) = v[e];
                }
            }
        }
        for (int i = tid; i < 15*512; i += 256) {
            int r = NTOK + (i >> 9);
            int c = i & 511;
            *(unsigned short*)(asT + r*1024 + ((c*2) ^ ((r&7)<<4))) = 0;
        }
    }
    __syncthreads();

    #pragma unroll
    for (int pass = 0; pass < 2; ++pass) {
        ffrag acc[4][4];   // [o-subtile][token-tile]
        #pragma unroll
        for (int q = 0; q < 4; ++q)
            #pragma unroll
            for (int t = 0; t < 4; ++t) { ffrag z = {0.f,0.f,0.f,0.f}; acc[q][t] = z; }

        const _Float16* wrow[4];
        #pragma unroll
        for (int q = 0; q < 4; ++q) {
            int ot = wid*8 + pass*4 + q;
            wrow[q] = wproj + (size_t)(ot*16 + l15) * 512;
        }

        hfrag Bf[2][4];
        #pragma unroll
        for (int q = 0; q < 4; ++q)
            Bf[0][q] = *(const hfrag*)(wrow[q] + g*8);

        #pragma unroll
        for (int ks = 0; ks < 16; ++ks) {
            if (ks < 15) {
                #pragma unroll
                for (int q = 0; q < 4; ++q)
                    Bf[(ks+1)&1][q] = *(const hfrag*)(wrow[q] + (ks+1)*32 + g*8);
            }
            hfrag Af[4];
            #pragma unroll
            for (int t = 0; t < 4; ++t) {
                int row = l15 + 16*t;
                Af[t] = *(const hfrag*)(asT + row*1024 + ((ks*64 + g*16) ^ ((l15&7)<<4)));
            }
            #pragma unroll
            for (int q = 0; q < 4; ++q)
                #pragma unroll
                for (int t = 0; t < 4; ++t)
                    acc[q][t] = __builtin_amdgcn_mfma_f32_16x16x32_f16(
                        Af[t], Bf[ks&1][q], acc[q][t], 0, 0, 0);
        }

        #pragma unroll
        for (int q = 0; q < 4; ++q) {
            int o = (wid*8 + pass*4 + q)*16 + l15;
            float pbv = proj_b[o];
            float* op = out + ((size_t)b*512 + o)*NTOK;
            #pragma unroll
            for (int t = 0; t < 4; ++t)
                #pragma unroll
                for (int i = 0; i < 4; ++i) {
                    int n = t*16 + 4*g + i;
                    if (n < NTOK)
                        op[n] = acc[q][t][i] + pbv;
                }
        }
    }
}

// ---------------------------------------------------------------------------
extern "C" void kernel_launch(void* const* d_in, const int* in_sizes, int n_in,
                              void* d_out, int out_size, void* d_ws, size_t ws_size,
                              hipStream_t stream) {
    const float* x      = (const float*)d_in[0];
    const float* qkv_w  = (const float*)d_in[1];
    const float* proj_w = (const float*)d_in[2];
    const float* proj_b = (const float*)d_in[3];
    const float* bias_t = (const float*)d_in[4];
    const int*   rel    = (const int*)d_in[5];
    float* out = (float*)d_out;

    char* ws = (char*)d_ws;
    _Float16* wqkv   = (_Float16*)(ws);
    _Float16* wproj  = (_Float16*)(ws + WPROJ_OFF);
    float*    biasf  = (float*)(ws + BIAS_OFF);
    _Float16* attout = (_Float16*)(ws + ATT_OFF);
    // requires ws_size >= ~105 MB (2228224 + 2048*512*49*2 bytes)

    const int prep_total = 1536*512 + 512*512 + 8*64*64;
    prep_kernel<<<(prep_total + 255)/256, 256, 0, stream>>>(
        qkv_w, proj_w, bias_t, rel, wqkv, wproj, biasf);
    attn_fused_kernel<<<BATCH, 256, 98304, stream>>>(x, wqkv, biasf, attout);
    proj_kernel<<<BATCH, 256, 65536, stream>>>(attout, wproj, proj_b, out);
}

// Round 3
// 990.906 us; speedup vs baseline: 1.3728x; 1.3728x over previous
//
#include <hip/hip_runtime.h>
#include <hip/hip_bf16.h>
#include <stdint.h>

// MultiHeadSelfAttention (Swin window attn): B=2048 windows, C=512, N=49, h=8, d=64.
// Round 3 = round 2 + hipFuncSetAttribute(MaxDynamicSharedMemorySize) hardening:
// single fused kernel, 512 threads (8 waves), wave-per-head.
//   Phase 0: stage x -> xsT [64 tok][512 ch] f16 swizzled (conflict-free writes).
//   Phase 1 (per wave, head=wid): Q,K,V GEMMs (per-wave 8KB LDS tile reused
//            sequentially Q->K->P->V^T), S=QK^T, reg softmax (+bias), PV.
//   Phase 2: O written over xsT as [tok][512] f16.
//   Phase 3: fused out-proj GEMM + bias -> fp32 out. 3 barriers total.
// ws: Wqkv f16 | Wproj f16 | bias[8][64][64] f32 (pad masked -1e9). ~2.2MB.

#define BATCH 2048
#define CIN 512
#define NTOK 49
#define NHEAD 8

typedef __attribute__((ext_vector_type(4))) float    ffrag;
typedef __attribute__((ext_vector_type(8))) _Float16 hfrag;
typedef __attribute__((ext_vector_type(4))) float    f32x4;

#define WQKV_BYTES  (1536*512*2)
#define WPROJ_OFF   ((size_t)WQKV_BYTES)
#define WPROJ_BYTES (512*512*2)
#define BIAS_OFF    (WPROJ_OFF + WPROJ_BYTES)
#define BIAS_BYTES  (8*64*64*4)

// ---------------------------------------------------------------- prep ------
__global__ void prep_kernel(const float* __restrict__ qkv_w,
                            const float* __restrict__ proj_w,
                            const float* __restrict__ bias_table,
                            const int*   __restrict__ rel_index,
                            _Float16* __restrict__ wqkv,
                            _Float16* __restrict__ wproj,
                            float*    __restrict__ biasf) {
    int idx = blockIdx.x * blockDim.x + threadIdx.x;
    const int NQ = 1536*512;
    const int NP = 512*512;
    if (idx < NQ) {
        wqkv[idx] = (_Float16)qkv_w[idx];
    } else if (idx < NQ + NP) {
        int i = idx - NQ;
        wproj[i] = (_Float16)proj_w[i];
    } else if (idx < NQ + NP + 8*64*64) {
        int i = idx - NQ - NP;
        int h = i >> 12;
        int n = (i >> 6) & 63;
        int m = i & 63;
        float v;
        if (m >= NTOK)      v = -1e9f;   // masked key columns (pad)
        else if (n >= NTOK) v = 0.0f;    // pad query rows: finite, discarded later
        else                v = bias_table[rel_index[n*NTOK + m]*NHEAD + h];
        biasf[i] = v;
    }
}

// -------------------------------------------------------- fused everything --
// LDS 128KB: xsT [64][512] f16 swizzled (64KB, later reused as O_s) +
//            8 per-wave 8KB tiles (Q -> K -> P -> V^T sequentially).
// Swizzle: byte_in_row ^= (row&7)<<4 ; rows are 1024B (xsT) / 128B (tile).
__global__ __launch_bounds__(512, 2) void mhsa_fused_kernel(
        const float* __restrict__ x,
        const _Float16* __restrict__ wqkv,
        const _Float16* __restrict__ wproj,
        const float* __restrict__ projb,
        const float* __restrict__ biasf,
        float* __restrict__ out) {
    extern __shared__ char lds[];
    char* xsT = lds;                              // 64KB; later O_s[64][512]

    const int b    = blockIdx.x;
    const int tid  = threadIdx.x;
    const int wid  = tid >> 6;                    // wave id == head id
    const int lane = tid & 63;
    const int l15  = lane & 15;
    const int g    = lane >> 4;
    char* tile = lds + 65536 + (wid << 13);       // per-wave 8KB

    // ---- Phase 0: stage x[b] ([512][49] f32) -> xsT[tok][ch] f16 -----------
    // lane == channel: writes to one token row span 128B = 32 banks (no conflict).
    {
        const int c = tid;
        const float* xc = x + (size_t)b * (CIN*NTOK) + (size_t)c * NTOK;
        const int cb = c << 1;
        #pragma unroll 7
        for (int t = 0; t < NTOK; ++t)
            *(_Float16*)(xsT + t*1024 + (cb ^ ((t&7)<<4))) = (_Float16)xc[t];
        #pragma unroll
        for (int t = NTOK; t < 64; ++t)
            *(_Float16*)(xsT + t*1024 + (cb ^ ((t&7)<<4))) = (_Float16)0.0f;
    }
    __syncthreads();

    const int h = wid;
    hfrag qa[8], kb[8], pa[8], vb[8];   // [mt*2+ksp], all indices compile-time

    // read 8 A/B fragments (rows 16*mt + l15, k-halves ksp) from per-wave tile
    auto read_frags = [&](hfrag* dst) {
        #pragma unroll
        for (int mt = 0; mt < 4; ++mt)
            #pragma unroll
            for (int ksp = 0; ksp < 2; ++ksp)
                dst[mt*2+ksp] = *(const hfrag*)(tile + (16*mt + l15)*128 +
                                  ((ksp*64 + g*16) ^ ((l15&7)<<4)));
    };

    // one QKV pass: 64 output channels (s,h), M=64 tok, K=512. acc 64 VGPR.
    auto qkv_pass = [&](int s, int trans) {
        ffrag acc[4][4];
        #pragma unroll
        for (int nt = 0; nt < 4; ++nt)
            #pragma unroll
            for (int mt = 0; mt < 4; ++mt) { ffrag z = {0.f,0.f,0.f,0.f}; acc[nt][mt] = z; }

        const _Float16* wb = wqkv + ((size_t)(s*512 + h*64 + l15))*512 + g*8;
        hfrag Bf[2][4];
        #pragma unroll
        for (int nt = 0; nt < 4; ++nt)
            Bf[0][nt] = *(const hfrag*)(wb + nt*8192);

        #pragma unroll
        for (int ks = 0; ks < 16; ++ks) {
            if (ks < 15) {
                #pragma unroll
                for (int nt = 0; nt < 4; ++nt)
                    Bf[(ks+1)&1][nt] = *(const hfrag*)(wb + nt*8192 + (ks+1)*32);
            }
            hfrag Af[4];
            #pragma unroll
            for (int mt = 0; mt < 4; ++mt)
                Af[mt] = *(const hfrag*)(xsT + (16*mt + l15)*1024 +
                           ((ks*64 + g*16) ^ ((l15&7)<<4)));
            #pragma unroll
            for (int nt = 0; nt < 4; ++nt)
                #pragma unroll
                for (int mt = 0; mt < 4; ++mt)
                    acc[nt][mt] = __builtin_amdgcn_mfma_f32_16x16x32_f16(
                        Af[mt], Bf[ks&1][nt], acc[nt][mt], 0, 0, 0);
        }
        // epilogue -> tile.  C/D layout: col=l15(outch), rows=4g+i (token).
        #pragma unroll
        for (int nt = 0; nt < 4; ++nt)
            #pragma unroll
            for (int mt = 0; mt < 4; ++mt)
                #pragma unroll
                for (int i = 0; i < 4; ++i) {
                    int tok = 16*mt + 4*g + i;
                    int d   = 16*nt + l15;
                    _Float16 v = (_Float16)acc[nt][mt][i];
                    if (!trans)   // [tok][d]
                        *(_Float16*)(tile + tok*128 + ((2*d) ^ ((tok&7)<<4))) = v;
                    else          // [d][tok]  (V^T for PV B-operand)
                        *(_Float16*)(tile + d*128 + ((2*tok) ^ ((d&7)<<4))) = v;
                }
    };

    // ---- Phase 1: per-wave attention ---------------------------------------
    qkv_pass(0, 0);  read_frags(qa);      // Q [tok][d] -> A-frags
    qkv_pass(1, 0);  read_frags(kb);      // K [tok][d] -> B-frags (l15 = ktok)

    // S = Q K^T  [qtok][ktok], acc 64 VGPR
    ffrag sacc[4][4];                      // [nt=ktok tile][mt=qtok tile]
    #pragma unroll
    for (int nt = 0; nt < 4; ++nt)
        #pragma unroll
        for (int mt = 0; mt < 4; ++mt) { ffrag z = {0.f,0.f,0.f,0.f}; sacc[nt][mt] = z; }
    #pragma unroll
    for (int nt = 0; nt < 4; ++nt)
        #pragma unroll
        for (int mt = 0; mt < 4; ++mt)
            #pragma unroll
            for (int ksp = 0; ksp < 2; ++ksp)
                sacc[nt][mt] = __builtin_amdgcn_mfma_f32_16x16x32_f16(
                    qa[mt*2+ksp], kb[nt*2+ksp], sacc[nt][mt], 0, 0, 0);

    // scale + relative-position bias (pad mask baked into biasf)
    const float* bh = biasf + (h << 12);
    #pragma unroll
    for (int nt = 0; nt < 4; ++nt)
        #pragma unroll
        for (int mt = 0; mt < 4; ++mt)
            #pragma unroll
            for (int i = 0; i < 4; ++i) {
                int n = 16*mt + 4*g + i, m = 16*nt + l15;
                sacc[nt][mt][i] = sacc[nt][mt][i]*0.125f + bh[(n<<6) + m];
            }

    // wave-parallel softmax over ktok (in-lane across nt, 16-lane shfl across l15)
    float rmax[4][4], rsum[4][4];
    #pragma unroll
    for (int mt = 0; mt < 4; ++mt)
        #pragma unroll
        for (int i = 0; i < 4; ++i)
            rmax[mt][i] = fmaxf(fmaxf(sacc[0][mt][i], sacc[1][mt][i]),
                                fmaxf(sacc[2][mt][i], sacc[3][mt][i]));
    #pragma unroll
    for (int off = 1; off <= 8; off <<= 1)
        #pragma unroll
        for (int mt = 0; mt < 4; ++mt)
            #pragma unroll
            for (int i = 0; i < 4; ++i)
                rmax[mt][i] = fmaxf(rmax[mt][i], __shfl_xor(rmax[mt][i], off));
    #pragma unroll
    for (int mt = 0; mt < 4; ++mt)
        #pragma unroll
        for (int i = 0; i < 4; ++i) rsum[mt][i] = 0.0f;
    #pragma unroll
    for (int nt = 0; nt < 4; ++nt)
        #pragma unroll
        for (int mt = 0; mt < 4; ++mt)
            #pragma unroll
            for (int i = 0; i < 4; ++i) {
                float p = __expf(sacc[nt][mt][i] - rmax[mt][i]);
                sacc[nt][mt][i] = p;
                rsum[mt][i] += p;
            }
    #pragma unroll
    for (int off = 1; off <= 8; off <<= 1)
        #pragma unroll
        for (int mt = 0; mt < 4; ++mt)
            #pragma unroll
            for (int i = 0; i < 4; ++i)
                rsum[mt][i] += __shfl_xor(rsum[mt][i], off);

    // write unnormalized P (f16) over tile (K-frags already in regs)
    #pragma unroll
    for (int nt = 0; nt < 4; ++nt)
        #pragma unroll
        for (int mt = 0; mt < 4; ++mt)
            #pragma unroll
            for (int i = 0; i < 4; ++i) {
                int n = 16*mt + 4*g + i, m = 16*nt + l15;
                *(_Float16*)(tile + n*128 + ((2*m) ^ ((n&7)<<4))) = (_Float16)sacc[nt][mt][i];
            }
    read_frags(pa);                       // P [qtok][ktok] -> A-frags

    float inv[4][4];
    #pragma unroll
    for (int mt = 0; mt < 4; ++mt)
        #pragma unroll
        for (int i = 0; i < 4; ++i) inv[mt][i] = 1.0f / rsum[mt][i];

    qkv_pass(2, 1);  read_frags(vb);      // V^T [d][tok] -> B-frags (l15 = d)

    // O = P V   [qtok][d], acc 64 VGPR
    ffrag oacc[4][4];                     // [dt][mt]
    #pragma unroll
    for (int dt = 0; dt < 4; ++dt)
        #pragma unroll
        for (int mt = 0; mt < 4; ++mt) { ffrag z = {0.f,0.f,0.f,0.f}; oacc[dt][mt] = z; }
    #pragma unroll
    for (int dt = 0; dt < 4; ++dt)
        #pragma unroll
        for (int mt = 0; mt < 4; ++mt)
            #pragma unroll
            for (int ksp = 0; ksp < 2; ++ksp)
                oacc[dt][mt] = __builtin_amdgcn_mfma_f32_16x16x32_f16(
                    pa[mt*2+ksp], vb[dt*2+ksp], oacc[dt][mt], 0, 0, 0);

    // ---- Phase 2: O -> O_s over xsT (channel = 64h + d), normalized --------
    __syncthreads();   // all waves done reading xsT
    #pragma unroll
    for (int dt = 0; dt < 4; ++dt)
        #pragma unroll
        for (int mt = 0; mt < 4; ++mt)
            #pragma unroll
            for (int i = 0; i < 4; ++i) {
                int tok = 16*mt + 4*g + i;
                int ch  = (h<<6) + 16*dt + l15;
                float v = oacc[dt][mt][i] * inv[mt][i];
                *(_Float16*)(xsT + tok*1024 + ((2*ch) ^ ((tok&7)<<4))) = (_Float16)v;
            }
    __syncthreads();

    // ---- Phase 3: out-proj: D[tok][o] = O_s[tok][:] . Wproj[o][:] ----------
    {
        ffrag acc[4][4];                  // [nt=outch tile][mt=tok tile]
        #pragma unroll
        for (int nt = 0; nt < 4; ++nt)
            #pragma unroll
            for (int mt = 0; mt < 4; ++mt) { ffrag z = {0.f,0.f,0.f,0.f}; acc[nt][mt] = z; }

        const _Float16* wb = wproj + ((size_t)((wid<<6) + l15))*512 + g*8;
        hfrag Bf[2][4];
        #pragma unroll
        for (int nt = 0; nt < 4; ++nt)
            Bf[0][nt] = *(const hfrag*)(wb + nt*8192);

        #pragma unroll
        for (int ks = 0; ks < 16; ++ks) {
            if (ks < 15) {
                #pragma unroll
                for (int nt = 0; nt < 4; ++nt)
                    Bf[(ks+1)&1][nt] = *(const hfrag*)(wb + nt*8192 + (ks+1)*32);
            }
            hfrag Af[4];
            #pragma unroll
            for (int mt = 0; mt < 4; ++mt)
                Af[mt] = *(const hfrag*)(xsT + (16*mt + l15)*1024 +
                           ((ks*64 + g*16) ^ ((l15&7)<<4)));
            #pragma unroll
            for (int nt = 0; nt < 4; ++nt)
                #pragma unroll
                for (int mt = 0; mt < 4; ++mt)
                    acc[nt][mt] = __builtin_amdgcn_mfma_f32_16x16x32_f16(
                        Af[mt], Bf[ks&1][nt], acc[nt][mt], 0, 0, 0);
        }

        #pragma unroll
        for (int nt = 0; nt < 4; ++nt) {
            int o = (wid<<6) + 16*nt + l15;
            float pb = projb[o];
            float* op = out + ((size_t)b*512 + o)*NTOK;
            #pragma unroll
            for (int mt = 0; mt < 4; ++mt)
                #pragma unroll
                for (int i = 0; i < 4; ++i) {
                    int n = 16*mt + 4*g + i;
                    if (n < NTOK) op[n] = acc[nt][mt][i] + pb;
                }
        }
    }
}

// ---------------------------------------------------------------------------
extern "C" void kernel_launch(void* const* d_in, const int* in_sizes, int n_in,
                              void* d_out, int out_size, void* d_ws, size_t ws_size,
                              hipStream_t stream) {
    const float* x      = (const float*)d_in[0];
    const float* qkv_w  = (const float*)d_in[1];
    const float* proj_w = (const float*)d_in[2];
    const float* proj_b = (const float*)d_in[3];
    const float* bias_t = (const float*)d_in[4];
    const int*   rel    = (const int*)d_in[5];
    float* out = (float*)d_out;

    char* ws = (char*)d_ws;
    _Float16* wqkv  = (_Float16*)(ws);
    _Float16* wproj = (_Float16*)(ws + WPROJ_OFF);
    float*    biasf = (float*)(ws + BIAS_OFF);

    // Allow 128KB dynamic LDS (default cap is 64KB). Host-side config call,
    // not a stream op — safe under graph capture; idempotent every call.
    (void)hipFuncSetAttribute((const void*)mhsa_fused_kernel,
                              hipFuncAttributeMaxDynamicSharedMemorySize,
                              131072);

    const int prep_total = 1536*512 + 512*512 + 8*64*64;
    prep_kernel<<<(prep_total + 255)/256, 256, 0, stream>>>(
        qkv_w, proj_w, bias_t, rel, wqkv, wproj, biasf);
    mhsa_fused_kernel<<<BATCH, 512, 131072, stream>>>(
        x, wqkv, wproj, proj_b, biasf, out);
}